// Round 10
// baseline (264.873 us; speedup 1.0000x reference)
//
#include <hip/hip_runtime.h>
#include <math.h>

#define NPTS   4096   // points per set (n == m)
#define NPROJ  2000   // projections
#define NB     1024   // threads per block (16 waves)
#define NMERGE 8192   // n + m
#define VPT    8      // values per thread (in registers)

// Bitonic local merge of 8 in-register elements, steps j=4..1, uniform direction.
__device__ __forceinline__ void local_merge(float v[VPT], bool asc) {
    #pragma unroll
    for (int j = 4; j >= 1; j >>= 1) {
        #pragma unroll
        for (int e = 0; e < VPT; ++e) {
            if ((e & j) == 0) {
                float a = v[e], b = v[e | j];
                float mn = fminf(a, b), mx = fmaxf(a, b);
                v[e]     = asc ? mn : mx;
                v[e | j] = asc ? mx : mn;
            }
        }
    }
}

// R10: natural (unswizzled) LDS layout. R9 hit VALUBusy 97% / occupancy 82%;
// the remaining cost is ADDRESS ARITHMETIC: keys[sw(x)] was ~6 VALU/access
// x ~130 accesses/thread. Natural layout: sorted-run stores are float4
// (ds_write_b128, 32B lane stride = 8 words/bank = balanced, swizzle-free);
// serial merges walk ++ptr (1 VALU) instead of recomputing swizzled addrs;
// bsearch probes cost 2 ops. Clustered merge reads become ~8-way bank
// conflicted -- accepted: DS pipe carried only ~11% load in R9.
// Values/comparisons unchanged => bit-identical results.
__global__ __launch_bounds__(NB) void swd_kernel(
    const float* __restrict__ Xs, const float* __restrict__ Xt,
    const float* __restrict__ Us, float* __restrict__ out)
{
    // keys: sorted u || sorted v (natural addressing). Exactly 32 KiB.
    // After the final merge it is dead and its head is reused:
    //   ired = (int*)keys [0..31]  : 16 wave mins, 16 wave maxs of level c
    //   red  = keys + 32  [32..47] : bisection sum per iteration (ds_add)
    //   wred = keys + 48  [48..63] : final 16 wave partials
    __shared__ float keys[NMERGE];
    float4* k4 = (float4*)keys;

    const int tid  = threadIdx.x;
    const int arr  = tid >> 9;       // 0 = Xs half, 1 = Xt half
    const int c    = tid & 511;      // chunk index within this array (8 elems/chunk)
    const int lane = tid & 63;
    const int wid  = tid >> 6;       // 0..15
    const int p    = blockIdx.x;

    const float u00 = Us[p*6+0], u01 = Us[p*6+1];
    const float u10 = Us[p*6+2], u11 = Us[p*6+3];
    const float u20 = Us[p*6+4], u21 = Us[p*6+5];

    const float pi_f   = 3.14159265358979323846f;
    const float inv2pi = 0.15915494309189535f;

    const float* __restrict__ X = arr ? Xt : Xs;

    // ---- angles into registers (atan2 is scale-invariant; F.normalize skipped) ----
    float v[VPT];
    {
        const float4* X4 = (const float4*)(X + c * (VPT * 3));  // 24 floats, 16B aligned
        #pragma unroll
        for (int t = 0; t < 2; ++t) {
            float4 q0 = X4[t*3+0], q1 = X4[t*3+1], q2 = X4[t*3+2];
            #define ANG(x,y,z) ((atan2f(-((x)*u01+(y)*u11+(z)*u21), \
                                        -((x)*u00+(y)*u10+(z)*u20)) + pi_f) * inv2pi)
            v[t*4+0] = ANG(q0.x, q0.y, q0.z);
            v[t*4+1] = ANG(q0.w, q1.x, q1.y);
            v[t*4+2] = ANG(q1.z, q1.w, q2.x);
            v[t*4+3] = ANG(q2.y, q2.z, q2.w);
            #undef ANG
        }
    }

    // ---- phases k=2..4: intra-thread, compile-time directions ----
    #pragma unroll
    for (int k = 2; k <= 4; k <<= 1) {
        #pragma unroll
        for (int j = k >> 1; j >= 1; j >>= 1) {
            #pragma unroll
            for (int e = 0; e < VPT; ++e) {
                if ((e & j) == 0) {
                    bool asc = ((e & k) == 0);
                    float a = v[e], b = v[e | j];
                    float mn = fminf(a, b), mx = fmaxf(a, b);
                    v[e]     = asc ? mn : mx;
                    v[e | j] = asc ? mx : mn;
                }
            }
        }
    }

    // ---- phase k=8: fully local, direction uniform per thread ----
    local_merge(v, (c & 1) == 0);

    // ---- phases k=16..512: within-wave shfl_xor exchanges + local merge ----
    // g = c*8 + e; asc = ((g & k)==0) = ((c & (k>>3))==0). k=512 forced
    // ascending (each aligned 512-block is asc-256||desc-256 = bitonic), so
    // all 16 wave-runs emerge ascending & merge-ready.
    #pragma unroll
    for (int k = 16; k <= 512; k <<= 1) {
        bool asc = (k == 512) || ((c & (k >> 3)) == 0);
        #pragma unroll
        for (int d = k >> 4; d >= 1; d >>= 1) {     // j = k/2 .. 8
            bool keepmin = (((c & d) == 0) == asc);
            #pragma unroll
            for (int e = 0; e < VPT; ++e) {
                float o = __shfl_xor(v[e], d, 64);
                v[e] = keepmin ? fminf(v[e], o) : fmaxf(v[e], o);
            }
        }
        local_merge(v, asc);
    }

    // ---- store the 16 ascending 512-runs (vectorized, conflict-balanced) ----
    k4[tid*2+0] = make_float4(v[0], v[1], v[2], v[3]);
    k4[tid*2+1] = make_float4(v[4], v[5], v[6], v[7]);
    __syncthreads();

    // ---- merge-path rounds: 512->1024->2048->4096 within each half ----
    // Output identity: Ab + dd = tid*8, so float4 writes land back in place.
    #define MERGE_ROUND(L, AB, DD)                                          \
    {                                                                       \
        const int Ab = (AB);                                                \
        const int Bb = Ab + (L);                                            \
        const int dd = (DD);                                                \
        int lo = dd > (L) ? dd - (L) : 0;                                   \
        int hi = dd < (L) ? dd : (L);                                       \
        while (lo < hi) {                                                   \
            int mid = (lo + hi) >> 1;                                       \
            if (keys[Ab + mid] <= keys[Bb + (dd - 1 - mid)])                \
                lo = mid + 1; else hi = mid;                                \
        }                                                                   \
        int i = lo, j = dd - lo;                                            \
        const float INFV = __builtin_inff();                                \
        const float* pu = &keys[Ab + i];                                    \
        const float* pv = &keys[Bb + j];                                    \
        float cu = (i < (L)) ? *pu : INFV;                                  \
        float cv = (j < (L)) ? *pv : INFV;                                  \
        _Pragma("unroll")                                                   \
        for (int s = 0; s < VPT; ++s) {                                     \
            bool take = (cu <= cv);                                         \
            v[s] = fminf(cu, cv);                                           \
            if (take) { ++i; ++pu; cu = (i < (L)) ? *pu : INFV; }           \
            else      { ++j; ++pv; cv = (j < (L)) ? *pv : INFV; }           \
        }                                                                   \
        __syncthreads();                                                    \
        k4[tid*2+0] = make_float4(v[0], v[1], v[2], v[3]);                  \
        k4[tid*2+1] = make_float4(v[4], v[5], v[6], v[7]);                  \
        __syncthreads();                                                    \
    }

    MERGE_ROUND(512,  arr * 4096 + (c >> 7) * 1024, (c & 127) * VPT)
    MERGE_ROUND(1024, arr * 4096 + (c >> 8) * 2048, (c & 255) * VPT)
    MERGE_ROUND(2048, arr * 4096,                   c * VPT)
    #undef MERGE_ROUND
    // keys now holds: sorted u at [0,4096), sorted v at [4096,8192).

    // ---- merge-path merge of u||v; (delta, level-offset) into registers ----
    int c_init;
    int offmin = 16, offmax = -16;                   // per-thread range of c offsets
    float offf[VPT];
    {
        const int d0 = tid * VPT;
        int lo = d0 > NPTS ? d0 - NPTS : 0;
        int hi = d0 < NPTS ? d0 : NPTS;
        while (lo < hi) {                     // ties: u first (stable argsort)
            int mid = (lo + hi) >> 1;
            if (keys[mid] <= keys[NPTS + (d0 - 1 - mid)]) lo = mid + 1; else hi = mid;
        }
        int i = lo, j = d0 - lo;
        c_init = i - j;
        const float FMAXV = 3.402823466e+38f;
        const float* pu = &keys[i];
        const float* pv = &keys[NPTS + j];
        float cu = (i < NPTS) ? *pu : FMAXV;
        float cv = (j < NPTS) ? *pv : FMAXV;
        #pragma unroll
        for (int s = 0; s < VPT; ++s) {
            float cur;
            if (cu <= cv) { cur = cu; ++i; ++pu; cu = (i < NPTS) ? *pu : FMAXV; }
            else          { cur = cv; ++j; ++pv; cv = (j < NPTS) ? *pv : FMAXV; }
            float nxt = fminf(cu, cv);
            if (nxt == FMAXV) nxt = 1.0f;     // vals_pad appends 1.0
            v[s] = nxt - cur;                 // delta (>= 0)
            int off = (i - j) - c_init;       // in [-8, 8]
            offmin = min(offmin, off);
            offmax = max(offmax, off);
            offf[s] = (float)off;
        }
    }

    __syncthreads();   // keys reads done everywhere; safe to reuse keys as scratch
    int*   ired = (int*)keys;       // [0..31]: 16 wave mins, 16 wave maxs
    float* red  = keys + 32;        // [32..47]: per-iteration bisection sums
    float* wred = keys + 48;        // [48..63]: final wave partials

    // ---- block min/max of level c ----
    int cmn = c_init + offmin, cmx = c_init + offmax;
    #pragma unroll
    for (int o = 32; o >= 1; o >>= 1) {
        cmn = min(cmn, __shfl_xor(cmn, o, 64));
        cmx = max(cmx, __shfl_xor(cmx, o, 64));
    }
    if (lane == 0) { ired[wid] = cmn; ired[16 + wid] = cmx; }
    if (tid < 16) red[tid] = 0.0f;            // zero bisection accumulators
    __syncthreads();
    cmn = ired[0]; cmx = ired[16];
    #pragma unroll
    for (int w = 1; w < 16; ++w) {
        cmn = min(cmn, ired[w]);
        cmx = max(cmx, ired[16 + w]);
    }

    // ---- level median c* via integer bisection over attained range ----
    // c* = smallest c with W(<= c) >= 0.5. Invariant: W(lo) < 0.5 <= W(hi).
    int lo_c = cmn - 1, hi_c = cmx;
    int it = 0;
    #pragma unroll 1
    while (hi_c - lo_c > 1) {
        const int mid = (lo_c + hi_c) >> 1;   // uniform across block
        const float thrf = (float)(mid - c_init);
        float s_loc = 0.0f;
        #pragma unroll
        for (int s = 0; s < VPT; ++s)
            s_loc += (offf[s] <= thrf) ? v[s] : 0.0f;
        #pragma unroll
        for (int o = 32; o >= 1; o >>= 1) s_loc += __shfl_down(s_loc, o, 64);
        if (lane == 0) atomicAdd(&red[it], s_loc);   // ds_add_f32, 16 lane0s
        __syncthreads();
        float S = red[it];                           // broadcast read
        if (S >= 0.5f) hi_c = mid; else lo_c = mid;
        ++it;
    }
    const int cstar = hi_c;

    // ---- w1 = (1/4096) * sum delta * |c - c*| ----
    float part = 0.0f;
    {
        const float thrf = (float)(cstar - c_init);
        #pragma unroll
        for (int s = 0; s < VPT; ++s)
            part += v[s] * fabsf(offf[s] - thrf);   // |x| is a free input modifier
    }
    #pragma unroll
    for (int o = 32; o >= 1; o >>= 1) part += __shfl_down(part, o, 64);
    if (lane == 0) wred[wid] = part;
    __syncthreads();
    if (tid == 0) {
        float w1 = 0.0f;
        #pragma unroll
        for (int w = 0; w < 16; ++w) w1 += wred[w];
        w1 *= (1.0f / 4096.0f);
        atomicAdd(out, w1 * (1.0f / (float)NPROJ));
    }
}

extern "C" void kernel_launch(void* const* d_in, const int* in_sizes, int n_in,
                              void* d_out, int out_size, void* d_ws, size_t ws_size,
                              hipStream_t stream) {
    const float* Xs = (const float*)d_in[0];
    const float* Xt = (const float*)d_in[1];
    const float* Us = (const float*)d_in[2];
    float* out = (float*)d_out;

    hipMemsetAsync(out, 0, sizeof(float), stream);
    swd_kernel<<<NPROJ, NB, 0, stream>>>(Xs, Xt, Us, out);
}

// Round 11
// 217.769 us; speedup vs baseline: 1.2163x; 1.2163x over previous
//
#include <hip/hip_runtime.h>
#include <math.h>

#define NPTS   4096   // points per set (n == m)
#define NPROJ  2000   // projections
#define NB     1024   // threads per block (16 waves)
#define NMERGE 8192   // n + m
#define VPT    8      // values per thread (in registers)

// XOR swizzle: low-5 bits xor'd with chunk index (chunk = i>>5). Bijective.
// Strided store (thread t, elems 8t+e): each bank gets exactly 2 lanes (free).
__device__ __forceinline__ int sw(int i) {
    return i ^ ((i >> 5) & 31);
}

// Bitonic local merge of 8 in-register elements, steps j=4..1, uniform direction.
__device__ __forceinline__ void local_merge(float v[VPT], bool asc) {
    #pragma unroll
    for (int j = 4; j >= 1; j >>= 1) {
        #pragma unroll
        for (int e = 0; e < VPT; ++e) {
            if ((e & j) == 0) {
                float a = v[e], b = v[e | j];
                float mn = fminf(a, b), mx = fmaxf(a, b);
                v[e]     = asc ? mn : mx;
                v[e | j] = asc ? mx : mn;
            }
        }
    }
}

// R11: R9 layout restored (R10's natural layout regressed: quarter-bank float4
// stores + unexplained occupancy halving). Two layout-preserving changes:
// (1) ping-pong LDS buffers (64 KiB; 2 blocks/CU is already the wave cap, so
//     free) -> one barrier per merge round instead of two, and no barrier
//     before scratch reuse (scratch lives in the dead buffer);
// (2) branchless serial-merge steps: R9's divergent if/else paid both sides
//     (~22 VALU/step); select index+address, ONE guarded ds_read, cndmask
//     merges (~13 VALU/step). Same compares/ties => bit-identical values.
__global__ __launch_bounds__(NB) void swd_kernel(
    const float* __restrict__ Xs, const float* __restrict__ Xt,
    const float* __restrict__ Us, float* __restrict__ out)
{
    // Ping-pong: runs bufA -> bufB -> bufA -> bufB; final merge reads bufB,
    // scratch (ired/red/wred) reuses dead bufA.
    __shared__ float bufA[NMERGE];
    __shared__ float bufB[NMERGE];

    const int tid  = threadIdx.x;
    const int arr  = tid >> 9;       // 0 = Xs half, 1 = Xt half
    const int c    = tid & 511;      // chunk index within this array (8 elems/chunk)
    const int lane = tid & 63;
    const int wid  = tid >> 6;       // 0..15
    const int p    = blockIdx.x;

    const float u00 = Us[p*6+0], u01 = Us[p*6+1];
    const float u10 = Us[p*6+2], u11 = Us[p*6+3];
    const float u20 = Us[p*6+4], u21 = Us[p*6+5];

    const float pi_f   = 3.14159265358979323846f;
    const float inv2pi = 0.15915494309189535f;

    const float* __restrict__ X = arr ? Xt : Xs;

    // ---- angles into registers (atan2 is scale-invariant; F.normalize skipped) ----
    float v[VPT];
    {
        const float4* X4 = (const float4*)(X + c * (VPT * 3));  // 24 floats, 16B aligned
        #pragma unroll
        for (int t = 0; t < 2; ++t) {
            float4 q0 = X4[t*3+0], q1 = X4[t*3+1], q2 = X4[t*3+2];
            #define ANG(x,y,z) ((atan2f(-((x)*u01+(y)*u11+(z)*u21), \
                                        -((x)*u00+(y)*u10+(z)*u20)) + pi_f) * inv2pi)
            v[t*4+0] = ANG(q0.x, q0.y, q0.z);
            v[t*4+1] = ANG(q0.w, q1.x, q1.y);
            v[t*4+2] = ANG(q1.z, q1.w, q2.x);
            v[t*4+3] = ANG(q2.y, q2.z, q2.w);
            #undef ANG
        }
    }

    // ---- phases k=2..4: intra-thread, compile-time directions ----
    #pragma unroll
    for (int k = 2; k <= 4; k <<= 1) {
        #pragma unroll
        for (int j = k >> 1; j >= 1; j >>= 1) {
            #pragma unroll
            for (int e = 0; e < VPT; ++e) {
                if ((e & j) == 0) {
                    bool asc = ((e & k) == 0);
                    float a = v[e], b = v[e | j];
                    float mn = fminf(a, b), mx = fmaxf(a, b);
                    v[e]     = asc ? mn : mx;
                    v[e | j] = asc ? mx : mn;
                }
            }
        }
    }

    // ---- phase k=8: fully local, direction uniform per thread ----
    local_merge(v, (c & 1) == 0);

    // ---- phases k=16..512: within-wave shfl_xor exchanges + local merge ----
    // k=512 forced ascending (each aligned 512-block is bitonic there), so
    // all 16 wave-runs emerge ascending & merge-ready.
    #pragma unroll
    for (int k = 16; k <= 512; k <<= 1) {
        bool asc = (k == 512) || ((c & (k >> 3)) == 0);
        #pragma unroll
        for (int d = k >> 4; d >= 1; d >>= 1) {     // j = k/2 .. 8
            bool keepmin = (((c & d) == 0) == asc);
            #pragma unroll
            for (int e = 0; e < VPT; ++e) {
                float o = __shfl_xor(v[e], d, 64);
                v[e] = keepmin ? fminf(v[e], o) : fmaxf(v[e], o);
            }
        }
        local_merge(v, asc);
    }

    // ---- store the 16 ascending 512-runs into bufA ----
    #pragma unroll
    for (int e = 0; e < VPT; ++e) bufA[sw(tid * VPT + e)] = v[e];
    __syncthreads();

    // ---- merge-path rounds: 512->1024->2048->4096 within each half ----
    // Read SRC, write DST, ONE barrier. Branchless serial step: one guarded
    // ds_read per step; address masked so the speculative load is in-bounds.
    #define MERGE_ROUND(SRC, DST, L, AB, DD)                                \
    {                                                                       \
        const int Ab = (AB);                                                \
        const int Bb = Ab + (L);                                            \
        const int dd = (DD);                                                \
        int lo = dd > (L) ? dd - (L) : 0;                                   \
        int hi = dd < (L) ? dd : (L);                                       \
        while (lo < hi) {                                                   \
            int mid = (lo + hi) >> 1;                                       \
            if (SRC[sw(Ab + mid)] <= SRC[sw(Bb + (dd - 1 - mid))])          \
                lo = mid + 1; else hi = mid;                                \
        }                                                                   \
        int i = lo, j = dd - lo;                                            \
        const float INFV = __builtin_inff();                                \
        float cu = (i < (L)) ? SRC[sw(Ab + i)] : INFV;                      \
        float cv = (j < (L)) ? SRC[sw(Bb + j)] : INFV;                      \
        _Pragma("unroll")                                                   \
        for (int s = 0; s < VPT; ++s) {                                     \
            bool take = (cu <= cv);                                         \
            v[s] = fminf(cu, cv);                                           \
            i += take; j += !take;                                          \
            int sel  = take ? i : j;                                        \
            int badd = (take ? (Ab + i) : (Bb + j)) & (NMERGE - 1);         \
            float tmp = SRC[sw(badd)];                                      \
            float val = (sel < (L)) ? tmp : INFV;                           \
            cu = take ? val : cu;                                           \
            cv = take ? cv : val;                                           \
        }                                                                   \
        _Pragma("unroll")                                                   \
        for (int e = 0; e < VPT; ++e) DST[sw(tid * VPT + e)] = v[e];        \
        __syncthreads();                                                    \
    }

    MERGE_ROUND(bufA, bufB, 512,  arr * 4096 + (c >> 7) * 1024, (c & 127) * VPT)
    MERGE_ROUND(bufB, bufA, 1024, arr * 4096 + (c >> 8) * 2048, (c & 255) * VPT)
    MERGE_ROUND(bufA, bufB, 2048, arr * 4096,                   c * VPT)
    #undef MERGE_ROUND
    // bufB now holds: sorted u at [0,4096), sorted v at [4096,8192).

    // ---- merge-path merge of u||v (branchless); (delta, level-offset) to regs ----
    int c_init;
    int offmin = 16, offmax = -16;                   // per-thread range of c offsets
    float offf[VPT];
    {
        const int d0 = tid * VPT;
        int lo = d0 > NPTS ? d0 - NPTS : 0;
        int hi = d0 < NPTS ? d0 : NPTS;
        while (lo < hi) {                     // ties: u first (stable argsort)
            int mid = (lo + hi) >> 1;
            if (bufB[sw(mid)] <= bufB[sw(NPTS + (d0 - 1 - mid))]) lo = mid + 1; else hi = mid;
        }
        int i = lo, j = d0 - lo;
        c_init = i - j;
        const float FMAXV = 3.402823466e+38f;
        float cu = (i < NPTS) ? bufB[sw(i)] : FMAXV;
        float cv = (j < NPTS) ? bufB[sw(NPTS + j)] : FMAXV;
        #pragma unroll
        for (int s = 0; s < VPT; ++s) {
            bool take = (cu <= cv);
            float cur = fminf(cu, cv);
            i += take; j += !take;
            int sel  = take ? i : j;
            int badd = (take ? i : (NPTS + j)) & (NMERGE - 1);
            float tmp = bufB[sw(badd)];
            float val = (sel < NPTS) ? tmp : FMAXV;
            cu = take ? val : cu;
            cv = take ? cv : val;
            float nxt = fminf(cu, cv);
            if (nxt == FMAXV) nxt = 1.0f;     // vals_pad appends 1.0
            v[s] = nxt - cur;                 // delta (>= 0)
            int off = (i - j) - c_init;       // in [-8, 8]
            offmin = min(offmin, off);
            offmax = max(offmax, off);
            offf[s] = (float)off;
        }
    }

    // bufA is dead (last read in round 2->bufB... last read was MERGE_ROUND 3's
    // source = bufA, completed before that round's barrier). Scratch there; no
    // extra barrier needed before these writes.
    int*   ired = (int*)bufA;       // [0..31]: 16 wave mins, 16 wave maxs
    float* red  = bufA + 32;        // [32..47]: per-iteration bisection sums
    float* wred = bufA + 48;        // [48..63]: final wave partials

    // ---- block min/max of level c ----
    int cmn = c_init + offmin, cmx = c_init + offmax;
    #pragma unroll
    for (int o = 32; o >= 1; o >>= 1) {
        cmn = min(cmn, __shfl_xor(cmn, o, 64));
        cmx = max(cmx, __shfl_xor(cmx, o, 64));
    }
    if (lane == 0) { ired[wid] = cmn; ired[16 + wid] = cmx; }
    if (tid < 16) red[tid] = 0.0f;            // zero bisection accumulators
    __syncthreads();
    cmn = ired[0]; cmx = ired[16];
    #pragma unroll
    for (int w = 1; w < 16; ++w) {
        cmn = min(cmn, ired[w]);
        cmx = max(cmx, ired[16 + w]);
    }

    // ---- level median c* via integer bisection over attained range ----
    // c* = smallest c with W(<= c) >= 0.5. Invariant: W(lo) < 0.5 <= W(hi).
    int lo_c = cmn - 1, hi_c = cmx;
    int it = 0;
    #pragma unroll 1
    while (hi_c - lo_c > 1) {
        const int mid = (lo_c + hi_c) >> 1;   // uniform across block
        const float thrf = (float)(mid - c_init);
        float s_loc = 0.0f;
        #pragma unroll
        for (int s = 0; s < VPT; ++s)
            s_loc += (offf[s] <= thrf) ? v[s] : 0.0f;
        #pragma unroll
        for (int o = 32; o >= 1; o >>= 1) s_loc += __shfl_down(s_loc, o, 64);
        if (lane == 0) atomicAdd(&red[it], s_loc);   // ds_add_f32, 16 lane0s
        __syncthreads();
        float S = red[it];                           // broadcast read
        if (S >= 0.5f) hi_c = mid; else lo_c = mid;
        ++it;
    }
    const int cstar = hi_c;

    // ---- w1 = (1/4096) * sum delta * |c - c*| ----
    float part = 0.0f;
    {
        const float thrf = (float)(cstar - c_init);
        #pragma unroll
        for (int s = 0; s < VPT; ++s)
            part += v[s] * fabsf(offf[s] - thrf);   // |x| is a free input modifier
    }
    #pragma unroll
    for (int o = 32; o >= 1; o >>= 1) part += __shfl_down(part, o, 64);
    if (lane == 0) wred[wid] = part;
    __syncthreads();
    if (tid == 0) {
        float w1 = 0.0f;
        #pragma unroll
        for (int w = 0; w < 16; ++w) w1 += wred[w];
        w1 *= (1.0f / 4096.0f);
        atomicAdd(out, w1 * (1.0f / (float)NPROJ));
    }
}

extern "C" void kernel_launch(void* const* d_in, const int* in_sizes, int n_in,
                              void* d_out, int out_size, void* d_ws, size_t ws_size,
                              hipStream_t stream) {
    const float* Xs = (const float*)d_in[0];
    const float* Xt = (const float*)d_in[1];
    const float* Us = (const float*)d_in[2];
    float* out = (float*)d_out;

    hipMemsetAsync(out, 0, sizeof(float), stream);
    swd_kernel<<<NPROJ, NB, 0, stream>>>(Xs, Xt, Us, out);
}